// Round 1
// baseline (331.132 us; speedup 1.0000x reference)
//
#include <hip/hip_runtime.h>
#include <math.h>

// Problem geometry
#define Bn_ 4
#define W_ 512
#define H_ 512
#define HW_ 262144          // 512*512 = 2^18
#define CHW_ 786432         // 3*HW
#define NPLANE 12           // B*C
#define NCHUNK 32           // chunks per plane for reductions

// d_out offsets (floats), return order:
// (Bn, tn, Jn, G, Hn, Pn, Qn, un, vn, Xn, Yn, gamma_3)
#define O_Bn 0
#define O_tn 3145728
#define O_Jn 6291456
#define O_G  9437184
#define O_Hn 12582912
#define O_Pn 15728640
#define O_Qn 16777216
#define O_un 17825792
#define O_vn 20971520
#define O_Xn 24117248
#define O_Yn 27262976
#define O_g3 30408704

// lam constants
#define LAM1 1.0f
#define LAM2 0.7f
#define LAM3 0.3f

__device__ __forceinline__ float blockReduceSum256(float v) {
    #pragma unroll
    for (int off = 32; off; off >>= 1) v += __shfl_down(v, off, 64);
    __shared__ float s[4];
    int lane = threadIdx.x & 63, w = threadIdx.x >> 6;
    if (!lane) s[w] = v;
    __syncthreads();
    if (threadIdx.x == 0) v = s[0] + s[1] + s[2] + s[3];
    return v;
}

// ---- Pass A1: partial sums of J per (b,c) plane ----
__global__ __launch_bounds__(256) void kSumJ(const float* __restrict__ J,
                                             float* __restrict__ sums) {
    int blk = blockIdx.x;              // 0..383
    int plane = blk >> 5, chunk = blk & 31;
    const float4* p = (const float4*)(J + (size_t)plane * HW_ + chunk * 8192);
    float s = 0.f;
    #pragma unroll
    for (int k = 0; k < 8; ++k) {
        float4 v = p[threadIdx.x + k * 256];
        s += (v.x + v.y) + (v.z + v.w);
    }
    s = blockReduceSum256(s);
    if (threadIdx.x == 0) sums[blk] = s;
}

// ---- Pass A2: finalize means, stable 3-argsort, alpha/idx2, gamma_3 out ----
__global__ void kFinalizeJ(const float* __restrict__ sums,
                           float* __restrict__ alpha, int* __restrict__ idx2,
                           const float* __restrict__ g3p, float* __restrict__ outg3) {
    __shared__ float mean[12];
    int t = threadIdx.x;
    if (t < 12) {
        float s = 0.f;
        for (int k = 0; k < 32; ++k) s += sums[t * 32 + k];
        mean[t] = s * (1.0f / (float)HW_);
    }
    __syncthreads();
    if (t < 4) {
        float m0 = mean[t * 3 + 0], m1 = mean[t * 3 + 1], m2 = mean[t * 3 + 2];
        float m[3] = {m0, m1, m2};
        int r[3];
        #pragma unroll
        for (int i = 0; i < 3; ++i) {
            int ri = 0;
            #pragma unroll
            for (int j = 0; j < 3; ++j)
                if (j != i && (m[j] < m[i] || (m[j] == m[i] && j < i))) ri++;
            r[i] = ri;   // ascending stable rank
        }
        int idx[3]; float ms[3];
        #pragma unroll
        for (int i = 0; i < 3; ++i) { idx[r[i]] = i; ms[r[i]] = m[i]; }
        idx2[t] = idx[2];
        float a[3] = {0.f, 0.f, 0.f};
        a[idx[1]] = ms[2] - ms[1];
        a[idx[0]] = ms[2] - ms[0];
        #pragma unroll
        for (int c = 0; c < 3; ++c) alpha[t * 3 + c] = a[c];
    }
    if (t == 0) *outg3 = g3p[0];
}

// ---- Pass B1: partial sums of the Bn expression per (b,c) ----
__global__ __launch_bounds__(256) void kSumB(const float* __restrict__ J,
                                             const float* __restrict__ tt,
                                             const float* __restrict__ B_p,
                                             const float* __restrict__ I,
                                             const float* __restrict__ alpha,
                                             const int* __restrict__ idx2,
                                             float* __restrict__ sums) {
    int blk = blockIdx.x;
    int plane = blk >> 5, chunk = blk & 31;
    int b = plane / 3;
    float al = alpha[plane];
    size_t base = (size_t)plane * HW_ + chunk * 8192;
    size_t lbase = (size_t)(b * 3 + idx2[b]) * HW_ + chunk * 8192;
    const float4* Jp  = (const float4*)(J + base);
    const float4* Jlp = (const float4*)(J + lbase);
    const float4* tp  = (const float4*)(tt + base);
    const float4* Bp  = (const float4*)(B_p + base);
    const float4* Ip  = (const float4*)(I + base);
    float s = 0.f;
    #pragma unroll 4
    for (int k = 0; k < 8; ++k) {
        int o = threadIdx.x + k * 256;
        float4 j = Jp[o], jl = Jlp[o], tv = tp[o], bp = Bp[o], iv = Ip[o];
        float jm, omt;
        jm = j.x + al * jl.x; omt = 1.f - tv.x;
        s += (LAM3 * bp.x - (jm * tv.x - iv.x) * omt) / (omt * omt + LAM3);
        jm = j.y + al * jl.y; omt = 1.f - tv.y;
        s += (LAM3 * bp.y - (jm * tv.y - iv.y) * omt) / (omt * omt + LAM3);
        jm = j.z + al * jl.z; omt = 1.f - tv.z;
        s += (LAM3 * bp.z - (jm * tv.z - iv.z) * omt) / (omt * omt + LAM3);
        jm = j.w + al * jl.w; omt = 1.f - tv.w;
        s += (LAM3 * bp.w - (jm * tv.w - iv.w) * omt) / (omt * omt + LAM3);
    }
    s = blockReduceSum256(s);
    if (threadIdx.x == 0) sums[blk] = s;
}

__global__ void kFinalizeB(const float* __restrict__ sums, float* __restrict__ BnS) {
    int t = threadIdx.x;
    if (t < 12) {
        float s = 0.f;
        for (int k = 0; k < 32; ++k) s += sums[t * 32 + k];
        BnS[t] = s * (1.0f / (float)HW_);
    }
}

// ---- Pass C: fused elementwise. One thread = one (b, pixel), all 3 channels ----
__global__ __launch_bounds__(256) void kMain(
    const float* __restrict__ I, const float* __restrict__ t_p,
    const float* __restrict__ Hm, const float* __restrict__ Xm,
    const float* __restrict__ J, const float* __restrict__ u,
    const float* __restrict__ v, const float* __restrict__ Y,
    const float* __restrict__ G,
    const float* __restrict__ g1p, const float* __restrict__ g2p,
    const float* __restrict__ g3p, const float* __restrict__ g4p,
    const float* __restrict__ g5p, const float* __restrict__ t1w,
    const float* __restrict__ alpha, const int* __restrict__ idx2,
    const float* __restrict__ BnS,
    float* __restrict__ out)
{
    int id = blockIdx.x * 256 + threadIdx.x;   // 0 .. 4*HW-1
    int b = id >> 18, p = id & (HW_ - 1);
    float g1 = g1p[0], g2 = g2p[0], g3 = g3p[0], g4 = g4p[0], g5 = g5p[0];
    float wc0 = t1w[0], wc1 = t1w[1], wc2 = t1w[2];
    int i2 = idx2[b];
    float Jl = J[(size_t)(b * 3 + i2) * HW_ + p];

    float Iv[3], Bv[3], uv[3], vv[3], Yv[3], Gv[3];
    float wc[3] = {wc0, wc1, wc2};
    float t1 = 0.f;
    #pragma unroll
    for (int c = 0; c < 3; ++c) {
        size_t o = (size_t)(b * 3 + c) * HW_ + p;
        float Ic = I[o], tpc = t_p[o], Hc = Hm[o], Xc = Xm[o], Jc = J[o];
        float Jm = Jc + alpha[b * 3 + c] * Jl;
        float Bnv = BnS[b * 3 + c];
        float d = Jm - Bnv;
        float tnr = (LAM2 * tpc + g4 * Hc - (Bnv - Ic) * d - Xc) /
                    (d * d + LAM2 + g4);
        t1 += wc[c] * tnr;
        Iv[c] = Ic; Bv[c] = Bnv;
        uv[c] = u[o]; vv[c] = v[o]; Yv[c] = Y[o]; Gv[c] = G[o];
    }
    float cu = 1e30f, cv = 1e30f;
    float invDenJ = 1.f / (t1 * t1 + g3 + g4 + g5);
    float invDu = 1.f / (g1 + g4), invDv = 1.f / (g2 + g5);
    #pragma unroll
    for (int c = 0; c < 3; ++c) {
        size_t o = (size_t)(b * 3 + c) * HW_ + p;
        float Jn = (t1 * (Iv[c] - Bv[c] * (1.f - t1)) + g3 * Gv[c] + g4 * uv[c]
                    - g5 * vv[c] - Yv[c] + g5) * invDenJ;
        float un = (g1 * uv[c] + g4 * Jn) * invDu;
        float vn = (g2 * vv[c] - g5 * Jn + g5) * invDv;
        out[O_Bn + o] = Bv[c];
        out[O_tn + o] = t1;
        out[O_Jn + o] = Jn;
        out[O_G  + o] = Gv[c];
        out[O_un + o] = un;
        out[O_vn + o] = vn;
        out[O_Yn + o] = Yv[c] + g3 * (Jn - Gv[c]);
        cu = fminf(cu, un); cv = fminf(cv, vn);
    }
    // channel-min maps, staged in the Pn/Qn slots (overwritten later by kVMin)
    out[O_Pn + b * HW_ + p] = cu;
    out[O_Qn + b * HW_ + p] = cv;
}

// ---- Pass E1: horizontal 35-tap reflect min. Scratch -> Hn/Xn slots ----
__global__ __launch_bounds__(256) void kHMin(float* __restrict__ out) {
    __shared__ float row[546];   // 512 + 2*17
    int blk = blockIdx.x;                 // 0..4095
    int tensor = blk >> 11;               // 0: u, 1: v
    int rem = blk & 2047;
    int b = rem >> 9, y = rem & 511;
    const float* src = out + (tensor ? O_Qn : O_Pn) + b * HW_ + y * W_;
    float* dst = out + (tensor ? O_Xn : O_Hn) + b * HW_ + y * W_;
    for (int j = threadIdx.x; j < 546; j += 256) {
        int xx = j - 17;
        xx = xx < 0 ? -xx : (xx >= W_ ? 2 * W_ - 2 - xx : xx);
        row[j] = src[xx];
    }
    __syncthreads();
    for (int x = threadIdx.x; x < W_; x += 256) {
        float m = row[x];
        #pragma unroll
        for (int k = 1; k < 35; ++k) m = fminf(m, row[x + k]);
        dst[x] = m;
    }
}

// ---- Pass E2: vertical 35-tap reflect min + soft threshold -> Pn/Qn ----
__global__ __launch_bounds__(256) void kVMin(const float* __restrict__ g1p,
                                             float* __restrict__ out) {
    int tensor = blockIdx.x >> 12;        // grid 8192 = 2*4096
    int lid = ((blockIdx.x & 4095) << 8) + threadIdx.x;
    int b = lid >> 18, p = lid & (HW_ - 1);
    int y = p >> 9, x = p & 511;
    const float* R = out + (tensor ? O_Xn : O_Hn) + b * HW_;
    float m = 1e30f;
    #pragma unroll
    for (int k = 0; k < 35; ++k) {
        int yy = y + k - 17;
        yy = yy < 0 ? -yy : (yy >= H_ ? 2 * H_ - 2 - yy : yy);
        m = fminf(m, R[yy * W_ + x]);
    }
    float lam = 1.0f / g1p[0];            // lam4/g1 == lam5/g1 == 1/g1
    float s = (m > 0.f) ? 1.f : (m < 0.f ? -1.f : 0.f);
    float r = s * fmaxf(fabsf(m) - lam, 0.f);
    out[(tensor ? O_Qn : O_Pn) + b * HW_ + p] = r;
}

// ---- Pass D: 3x3 zero-pad conv (runs last, overwrites Hn/Xn scratch) ----
__global__ __launch_bounds__(256) void kConv(const float* __restrict__ Xm,
                                             const float* __restrict__ hw,
                                             const float* __restrict__ g4p,
                                             float* __restrict__ out) {
    __shared__ float w[81];
    if (threadIdx.x < 81) w[threadIdx.x] = hw[threadIdx.x];
    __syncthreads();
    int id = blockIdx.x * 256 + threadIdx.x;
    int b = id >> 18, p = id & (HW_ - 1);
    int y = p >> 9, x = p & 511;
    float g4 = g4p[0], ig4 = 1.f / g4;
    const float* tn = out + O_tn + (size_t)b * CHW_;    // channel 0 (tn is channel-constant)
    float acc0 = 0.f, acc1 = 0.f, acc2 = 0.f;
    #pragma unroll
    for (int ky = 0; ky < 3; ++ky) {
        int yy = y + ky - 1;
        if (yy < 0 || yy >= H_) continue;
        #pragma unroll
        for (int kx = 0; kx < 3; ++kx) {
            int xx = x + kx - 1;
            if (xx < 0 || xx >= W_) continue;
            int pp = yy * W_ + xx;
            float t1v = tn[pp];
            #pragma unroll
            for (int i = 0; i < 3; ++i) {
                float Av = t1v + Xm[(size_t)(b * 3 + i) * HW_ + pp] * ig4;
                int kk = i * 9 + ky * 3 + kx;
                acc0 += w[kk] * Av;
                acc1 += w[27 + kk] * Av;
                acc2 += w[54 + kk] * Av;
            }
        }
    }
    float t1c = tn[p];
    float acc[3] = {acc0, acc1, acc2};
    #pragma unroll
    for (int o = 0; o < 3; ++o) {
        size_t oo = (size_t)(b * 3 + o) * HW_ + p;
        out[O_Hn + oo] = acc[o];
        out[O_Xn + oo] = Xm[oo] + g4 * (t1c - acc[o]);
    }
}

extern "C" void kernel_launch(void* const* d_in, const int* in_sizes, int n_in,
                              void* d_out, int out_size, void* d_ws, size_t ws_size,
                              hipStream_t stream) {
    (void)in_sizes; (void)n_in; (void)out_size; (void)ws_size;
    const float* I   = (const float*)d_in[0];
    const float* t_p = (const float*)d_in[1];
    const float* B_p = (const float*)d_in[2];
    const float* tt  = (const float*)d_in[4];
    const float* J   = (const float*)d_in[5];
    const float* G   = (const float*)d_in[6];
    const float* Hm  = (const float*)d_in[7];
    const float* u   = (const float*)d_in[10];
    const float* v   = (const float*)d_in[11];
    const float* X   = (const float*)d_in[12];
    const float* Y   = (const float*)d_in[13];
    const float* g1  = (const float*)d_in[14];
    const float* g2  = (const float*)d_in[15];
    const float* g3  = (const float*)d_in[16];
    const float* g4  = (const float*)d_in[17];
    const float* g5  = (const float*)d_in[18];
    const float* t1w = (const float*)d_in[19];
    const float* hw  = (const float*)d_in[20];
    float* out = (float*)d_out;
    float* ws  = (float*)d_ws;

    float* sumJ  = ws;              // 384 floats
    float* sumB  = ws + 384;        // 384 floats
    float* alpha = ws + 768;        // 12 floats
    int*   idx2  = (int*)(ws + 784);// 4 ints
    float* BnS   = ws + 788;        // 12 floats

    kSumJ<<<384, 256, 0, stream>>>(J, sumJ);
    kFinalizeJ<<<1, 64, 0, stream>>>(sumJ, alpha, idx2, g3, out + O_g3);
    kSumB<<<384, 256, 0, stream>>>(J, tt, B_p, I, alpha, idx2, sumB);
    kFinalizeB<<<1, 64, 0, stream>>>(sumB, BnS);
    kMain<<<4096, 256, 0, stream>>>(I, t_p, Hm, X, J, u, v, Y, G,
                                    g1, g2, g3, g4, g5, t1w, alpha, idx2, BnS, out);
    kHMin<<<4096, 256, 0, stream>>>(out);
    kVMin<<<8192, 256, 0, stream>>>(g1, out);
    kConv<<<4096, 256, 0, stream>>>(X, hw, g4, out);
}

// Round 2
// 329.241 us; speedup vs baseline: 1.0057x; 1.0057x over previous
//
#include <hip/hip_runtime.h>
#include <math.h>

// Problem geometry
#define W_ 512
#define H_ 512
#define HW_ 262144          // 512*512 = 2^18
#define HW4_ 65536          // HW/4 (float4 units)
#define CHW_ 786432         // 3*HW

// d_out offsets (floats), return order:
// (Bn, tn, Jn, G, Hn, Pn, Qn, un, vn, Xn, Yn, gamma_3)
#define O_Bn 0
#define O_tn 3145728
#define O_Jn 6291456
#define O_G  9437184
#define O_Hn 12582912
#define O_Pn 15728640
#define O_Qn 16777216
#define O_un 17825792
#define O_vn 20971520
#define O_Xn 24117248
#define O_Yn 27262976
#define O_g3 30408704

#define LAM2 0.7f
#define LAM3 0.3f

// ---- Pass A: ONE fused reduction over I, t, B_p, J.
// Per batch b computes 15 sums: sJ[c] (3), S1[c] (3), S2[l][c] (9) where
//   den = (1-t_c)^2 + lam3
//   S1[c]   = sum[ (lam3*B_p - (J_c*t_c - I_c)*(1-t_c)) / den ]
//   S2[l][c]= sum[ J_l * t_c*(1-t_c) / den ]
// so Bn_mean[b,c] = (S1[c] - alpha_c * S2[idx2][c]) / HW  -- no alpha needed here.
// grid: 4 batches x 128 chunks = 512 blocks; chunk = 2048 px = 512 float4.
__global__ __launch_bounds__(256) void kRed(const float* __restrict__ J,
                                            const float* __restrict__ tt,
                                            const float* __restrict__ B_p,
                                            const float* __restrict__ I,
                                            float* __restrict__ sums) {
    int blk = blockIdx.x;              // 0..511
    int b = blk >> 7, chunk = blk & 127;
    size_t pb = (size_t)b * (CHW_ / 4);          // float4 index of batch start
    size_t cb = (size_t)chunk * 512;             // float4 offset within plane
    const float4* J4 = (const float4*)J;
    const float4* t4 = (const float4*)tt;
    const float4* B4 = (const float4*)B_p;
    const float4* I4 = (const float4*)I;

    float aJ[3] = {0.f, 0.f, 0.f};
    float a1[3] = {0.f, 0.f, 0.f};
    float a2[9] = {0.f, 0.f, 0.f, 0.f, 0.f, 0.f, 0.f, 0.f, 0.f};

    #pragma unroll
    for (int k = 0; k < 2; ++k) {
        size_t o = cb + threadIdx.x + k * 256;
        float4 j0 = J4[pb + 0 * HW4_ + o];
        float4 j1 = J4[pb + 1 * HW4_ + o];
        float4 j2 = J4[pb + 2 * HW4_ + o];
        #pragma unroll
        for (int c = 0; c < 3; ++c) {
            float4 tv = t4[pb + (size_t)c * HW4_ + o];
            float4 bp = B4[pb + (size_t)c * HW4_ + o];
            float4 iv = I4[pb + (size_t)c * HW4_ + o];
            float4 jc = (c == 0) ? j0 : (c == 1 ? j1 : j2);
#define REDC(m) { \
            float omt = 1.f - tv.m; \
            float r = 1.f / (omt * omt + LAM3); \
            float g = tv.m * omt * r; \
            aJ[c] += jc.m; \
            a1[c] += (LAM3 * bp.m - (jc.m * tv.m - iv.m) * omt) * r; \
            a2[0 * 3 + c] += j0.m * g; \
            a2[1 * 3 + c] += j1.m * g; \
            a2[2 * 3 + c] += j2.m * g; }
            REDC(x) REDC(y) REDC(z) REDC(w)
#undef REDC
        }
    }

    // block-reduce 15 values
    float vals[15];
    #pragma unroll
    for (int c = 0; c < 3; ++c) { vals[c] = aJ[c]; vals[3 + c] = a1[c]; }
    #pragma unroll
    for (int s = 0; s < 9; ++s) vals[6 + s] = a2[s];

    __shared__ float lds[4][15];
    int lane = threadIdx.x & 63, w = threadIdx.x >> 6;
    #pragma unroll
    for (int s = 0; s < 15; ++s) {
        float v = vals[s];
        #pragma unroll
        for (int off = 32; off; off >>= 1) v += __shfl_down(v, off, 64);
        if (lane == 0) lds[w][s] = v;
    }
    __syncthreads();
    if (threadIdx.x < 15) {
        int s = threadIdx.x;
        sums[blk * 16 + s] = lds[0][s] + lds[1][s] + lds[2][s] + lds[3][s];
    }
}

// ---- Pass B: finalize (1 block). Argsort means, alpha/idx2, BnS, gamma_3 out.
__global__ void kFin(const float* __restrict__ sums,
                     float* __restrict__ alpha, int* __restrict__ idx2,
                     float* __restrict__ BnS,
                     const float* __restrict__ g3p, float* __restrict__ outg3) {
    __shared__ float tot[4][15];
    int t = threadIdx.x;
    if (t < 60) {
        int b = t / 15, s = t % 15;
        const float* p = sums + (size_t)b * 128 * 16 + s;
        float acc = 0.f;
        for (int ch = 0; ch < 128; ++ch) acc += p[ch * 16];
        tot[b][s] = acc;
    }
    __syncthreads();
    if (t < 4) {
        const float invHW = 1.0f / (float)HW_;
        float m[3] = {tot[t][0] * invHW, tot[t][1] * invHW, tot[t][2] * invHW};
        int r[3];
        #pragma unroll
        for (int i = 0; i < 3; ++i) {
            int ri = 0;
            #pragma unroll
            for (int j = 0; j < 3; ++j)
                if (j != i && (m[j] < m[i] || (m[j] == m[i] && j < i))) ri++;
            r[i] = ri;   // ascending stable rank
        }
        int idx[3]; float ms[3];
        #pragma unroll
        for (int i = 0; i < 3; ++i) { idx[r[i]] = i; ms[r[i]] = m[i]; }
        idx2[t] = idx[2];
        float a[3] = {0.f, 0.f, 0.f};
        a[idx[1]] = ms[2] - ms[1];
        a[idx[0]] = ms[2] - ms[0];
        #pragma unroll
        for (int c = 0; c < 3; ++c) {
            alpha[t * 3 + c] = a[c];
            BnS[t * 3 + c] = (tot[t][3 + c] - a[c] * tot[t][6 + idx[2] * 3 + c]) * invHW;
        }
    }
    if (t == 0) *outg3 = g3p[0];
}

// ---- Pass C: fused elementwise, float4 (4 px/thread, all 3 channels) ----
__global__ __launch_bounds__(256) void kMain(
    const float* __restrict__ I, const float* __restrict__ t_p,
    const float* __restrict__ Hm, const float* __restrict__ Xm,
    const float* __restrict__ J, const float* __restrict__ u,
    const float* __restrict__ v, const float* __restrict__ Y,
    const float* __restrict__ G,
    const float* __restrict__ g1p, const float* __restrict__ g2p,
    const float* __restrict__ g3p, const float* __restrict__ g4p,
    const float* __restrict__ g5p, const float* __restrict__ t1w,
    const float* __restrict__ alpha, const int* __restrict__ idx2,
    const float* __restrict__ BnS,
    float* __restrict__ out)
{
    int id = blockIdx.x * 256 + threadIdx.x;   // 0 .. 262143
    int b = id >> 16, q = id & (HW4_ - 1);
    float g1 = g1p[0], g2 = g2p[0], g3 = g3p[0], g4 = g4p[0], g5 = g5p[0];
    float wc[3] = {t1w[0], t1w[1], t1w[2]};
    int i2 = idx2[b];
    size_t pb = (size_t)b * (CHW_ / 4);
    const float4* I4p = (const float4*)I;
    const float4* tp4p = (const float4*)t_p;
    const float4* H4p = (const float4*)Hm;
    const float4* X4p = (const float4*)Xm;
    const float4* J4p = (const float4*)J;
    const float4* u4p = (const float4*)u;
    const float4* v4p = (const float4*)v;
    const float4* Y4p = (const float4*)Y;
    const float4* G4p = (const float4*)G;
    float4* o4 = (float4*)out;

    float4 Jl = J4p[pb + (size_t)i2 * HW4_ + q];
    float4 t1 = make_float4(0.f, 0.f, 0.f, 0.f);
    float4 Isv[3]; float Bsv[3];
    const float den2 = LAM2 + g4;
    #pragma unroll
    for (int c = 0; c < 3; ++c) {
        size_t o = pb + (size_t)c * HW4_ + q;
        float4 I4 = I4p[o], tp4 = tp4p[o], H4 = H4p[o], X4 = X4p[o], Jv = J4p[o];
        float al = alpha[b * 3 + c], Bnv = BnS[b * 3 + c];
        float wcc = wc[c];
#define STEP1(m) { \
        float d_ = (Jv.m + al * Jl.m) - Bnv; \
        float tnr_ = (LAM2 * tp4.m + g4 * H4.m - (Bnv - I4.m) * d_ - X4.m) / (d_ * d_ + den2); \
        t1.m += wcc * tnr_; }
        STEP1(x) STEP1(y) STEP1(z) STEP1(w)
#undef STEP1
        Isv[c] = I4; Bsv[c] = Bnv;
    }
    float g345 = g3 + g4 + g5;
    float4 invDen;
    invDen.x = 1.f / (t1.x * t1.x + g345);
    invDen.y = 1.f / (t1.y * t1.y + g345);
    invDen.z = 1.f / (t1.z * t1.z + g345);
    invDen.w = 1.f / (t1.w * t1.w + g345);
    float invDu = 1.f / (g1 + g4), invDv = 1.f / (g2 + g5);
    float4 cu = make_float4(1e30f, 1e30f, 1e30f, 1e30f);
    float4 cv = cu;
    #pragma unroll
    for (int c = 0; c < 3; ++c) {
        size_t o = pb + (size_t)c * HW4_ + q;
        float4 u4 = u4p[o], v4 = v4p[o], Y4 = Y4p[o], G4 = G4p[o];
        float Bnv = Bsv[c];
        float4 Jn4, un4, vn4, Yn4;
#define STEP2(m) { \
        float Jn_ = (t1.m * (Isv[c].m - Bnv * (1.f - t1.m)) + g3 * G4.m + g4 * u4.m \
                     - g5 * v4.m - Y4.m + g5) * invDen.m; \
        float un_ = (g1 * u4.m + g4 * Jn_) * invDu; \
        float vn_ = (g2 * v4.m - g5 * Jn_ + g5) * invDv; \
        Jn4.m = Jn_; un4.m = un_; vn4.m = vn_; \
        Yn4.m = Y4.m + g3 * (Jn_ - G4.m); \
        cu.m = fminf(cu.m, un_); cv.m = fminf(cv.m, vn_); }
        STEP2(x) STEP2(y) STEP2(z) STEP2(w)
#undef STEP2
        o4[O_Bn / 4 + o] = make_float4(Bnv, Bnv, Bnv, Bnv);
        o4[O_tn / 4 + o] = t1;
        o4[O_Jn / 4 + o] = Jn4;
        o4[O_G  / 4 + o] = G4;
        o4[O_un / 4 + o] = un4;
        o4[O_vn / 4 + o] = vn4;
        o4[O_Yn / 4 + o] = Yn4;
    }
    // channel-min maps staged in Pn/Qn slots (overwritten later by kVMin)
    o4[O_Pn / 4 + (size_t)b * HW4_ + q] = cu;
    o4[O_Qn / 4 + (size_t)b * HW4_ + q] = cv;
}

// ---- Pass E1: horizontal 35-tap reflect min. Scratch -> Hn/Xn slots ----
__global__ __launch_bounds__(256) void kHMin(float* __restrict__ out) {
    __shared__ float row[546];   // 512 + 2*17
    int blk = blockIdx.x;                 // 0..4095
    int tensor = blk >> 11;               // 0: u, 1: v
    int rem = blk & 2047;
    int b = rem >> 9, y = rem & 511;
    const float* src = out + (tensor ? O_Qn : O_Pn) + b * HW_ + y * W_;
    float* dst = out + (tensor ? O_Xn : O_Hn) + b * HW_ + y * W_;
    for (int j = threadIdx.x; j < 546; j += 256) {
        int xx = j - 17;
        xx = xx < 0 ? -xx : (xx >= W_ ? 2 * W_ - 2 - xx : xx);
        row[j] = src[xx];
    }
    __syncthreads();
    for (int x = threadIdx.x; x < W_; x += 256) {
        float m = row[x];
        #pragma unroll
        for (int k = 1; k < 35; ++k) m = fminf(m, row[x + k]);
        dst[x] = m;
    }
}

// ---- Pass E2: vertical 35-tap reflect min + soft threshold -> Pn/Qn ----
__global__ __launch_bounds__(256) void kVMin(const float* __restrict__ g1p,
                                             float* __restrict__ out) {
    int tensor = blockIdx.x >> 12;        // grid 8192 = 2*4096
    int lid = ((blockIdx.x & 4095) << 8) + threadIdx.x;
    int b = lid >> 18, p = lid & (HW_ - 1);
    int y = p >> 9, x = p & 511;
    const float* R = out + (tensor ? O_Xn : O_Hn) + b * HW_;
    float m = 1e30f;
    #pragma unroll
    for (int k = 0; k < 35; ++k) {
        int yy = y + k - 17;
        yy = yy < 0 ? -yy : (yy >= H_ ? 2 * H_ - 2 - yy : yy);
        m = fminf(m, R[yy * W_ + x]);
    }
    float lam = 1.0f / g1p[0];            // lam4/g1 == lam5/g1 == 1/g1
    float s = (m > 0.f) ? 1.f : (m < 0.f ? -1.f : 0.f);
    float r = s * fmaxf(fabsf(m) - lam, 0.f);
    out[(tensor ? O_Qn : O_Pn) + b * HW_ + p] = r;
}

// ---- Pass D: 3x3 zero-pad conv (runs last, overwrites Hn/Xn scratch) ----
__global__ __launch_bounds__(256) void kConv(const float* __restrict__ Xm,
                                             const float* __restrict__ hw,
                                             const float* __restrict__ g4p,
                                             float* __restrict__ out) {
    __shared__ float w[81];
    if (threadIdx.x < 81) w[threadIdx.x] = hw[threadIdx.x];
    __syncthreads();
    int id = blockIdx.x * 256 + threadIdx.x;
    int b = id >> 18, p = id & (HW_ - 1);
    int y = p >> 9, x = p & 511;
    float g4 = g4p[0], ig4 = 1.f / g4;
    const float* tn = out + O_tn + (size_t)b * CHW_;    // channel 0 (tn is channel-constant)
    float acc0 = 0.f, acc1 = 0.f, acc2 = 0.f;
    #pragma unroll
    for (int ky = 0; ky < 3; ++ky) {
        int yy = y + ky - 1;
        if (yy < 0 || yy >= H_) continue;
        #pragma unroll
        for (int kx = 0; kx < 3; ++kx) {
            int xx = x + kx - 1;
            if (xx < 0 || xx >= W_) continue;
            int pp = yy * W_ + xx;
            float t1v = tn[pp];
            #pragma unroll
            for (int i = 0; i < 3; ++i) {
                float Av = t1v + Xm[(size_t)(b * 3 + i) * HW_ + pp] * ig4;
                int kk = i * 9 + ky * 3 + kx;
                acc0 += w[kk] * Av;
                acc1 += w[27 + kk] * Av;
                acc2 += w[54 + kk] * Av;
            }
        }
    }
    float t1c = tn[p];
    float acc[3] = {acc0, acc1, acc2};
    #pragma unroll
    for (int o = 0; o < 3; ++o) {
        size_t oo = (size_t)(b * 3 + o) * HW_ + p;
        out[O_Hn + oo] = acc[o];
        out[O_Xn + oo] = Xm[oo] + g4 * (t1c - acc[o]);
    }
}

extern "C" void kernel_launch(void* const* d_in, const int* in_sizes, int n_in,
                              void* d_out, int out_size, void* d_ws, size_t ws_size,
                              hipStream_t stream) {
    (void)in_sizes; (void)n_in; (void)out_size; (void)ws_size;
    const float* I   = (const float*)d_in[0];
    const float* t_p = (const float*)d_in[1];
    const float* B_p = (const float*)d_in[2];
    const float* tt  = (const float*)d_in[4];
    const float* J   = (const float*)d_in[5];
    const float* G   = (const float*)d_in[6];
    const float* Hm  = (const float*)d_in[7];
    const float* u   = (const float*)d_in[10];
    const float* v   = (const float*)d_in[11];
    const float* X   = (const float*)d_in[12];
    const float* Y   = (const float*)d_in[13];
    const float* g1  = (const float*)d_in[14];
    const float* g2  = (const float*)d_in[15];
    const float* g3  = (const float*)d_in[16];
    const float* g4  = (const float*)d_in[17];
    const float* g5  = (const float*)d_in[18];
    const float* t1w = (const float*)d_in[19];
    const float* hw  = (const float*)d_in[20];
    float* out = (float*)d_out;
    float* ws  = (float*)d_ws;

    float* sums  = ws;                 // 512*16 = 8192 floats
    float* alpha = ws + 8192;          // 12
    int*   idx2  = (int*)(ws + 8204);  // 4
    float* BnS   = ws + 8208;          // 12

    kRed<<<512, 256, 0, stream>>>(J, tt, B_p, I, sums);
    kFin<<<1, 64, 0, stream>>>(sums, alpha, idx2, BnS, g3, out + O_g3);
    kMain<<<1024, 256, 0, stream>>>(I, t_p, Hm, X, J, u, v, Y, G,
                                    g1, g2, g3, g4, g5, t1w, alpha, idx2, BnS, out);
    kHMin<<<4096, 256, 0, stream>>>(out);
    kVMin<<<8192, 256, 0, stream>>>(g1, out);
    kConv<<<4096, 256, 0, stream>>>(X, hw, g4, out);
}

// Round 4
// 322.709 us; speedup vs baseline: 1.0261x; 1.0202x over previous
//
#include <hip/hip_runtime.h>
#include <math.h>

// Problem geometry
#define W_ 512
#define H_ 512
#define HW_ 262144          // 512*512 = 2^18
#define HW4_ 65536          // HW/4 (float4 units)
#define CHW_ 786432         // 3*HW

// d_out offsets (floats), return order:
// (Bn, tn, Jn, G, Hn, Pn, Qn, un, vn, Xn, Yn, gamma_3)
#define O_Bn 0
#define O_tn 3145728
#define O_Jn 6291456
#define O_G  9437184
#define O_Hn 12582912
#define O_Pn 15728640
#define O_Qn 16777216
#define O_un 17825792
#define O_vn 20971520
#define O_Xn 24117248
#define O_Yn 27262976
#define O_g3 30408704

#define LAM2 0.7f
#define LAM3 0.3f

// ws layout (floats)
#define WS_SUMS   0        // 512*16 = 8192
#define WS_ALPHA  8192     // 12
#define WS_IDX2   8204     // 4 (ints)
#define WS_BNS    8208     // 12
#define WS_SCR    16384    // 2*4*HW = 2097152 floats (H-min scratch)

// native clang vector for nontemporal 16B stores (HIP float4 is a class type
// that __builtin_nontemporal_store rejects)
typedef float nfloat4 __attribute__((ext_vector_type(4)));

__device__ __forceinline__ void nt_store4(float4 v, float4* p) {
    nfloat4 nv; nv.x = v.x; nv.y = v.y; nv.z = v.z; nv.w = v.w;
    __builtin_nontemporal_store(nv, (nfloat4*)p);
}

// ---- Pass A: ONE fused reduction over I, t, B_p, J.
// Per batch b, 15 sums: sJ[c] (3), S1[c] (3), S2[l][c] (9):
//   den = (1-t_c)^2 + lam3
//   S1[c]    = sum[ (lam3*B_p - (J_c*t_c - I_c)*(1-t_c)) / den ]
//   S2[l][c] = sum[ J_l * t_c*(1-t_c) / den ]
// Bn_mean[b,c] = (S1[c] - alpha_c * S2[idx2][c]) / HW  (alpha applied in kFin)
__global__ __launch_bounds__(256) void kRed(const float* __restrict__ J,
                                            const float* __restrict__ tt,
                                            const float* __restrict__ B_p,
                                            const float* __restrict__ I,
                                            float* __restrict__ sums) {
    int blk = blockIdx.x;              // 0..511
    int b = blk >> 7, chunk = blk & 127;
    size_t pb = (size_t)b * (CHW_ / 4);
    size_t cb = (size_t)chunk * 512;
    const float4* J4 = (const float4*)J;
    const float4* t4 = (const float4*)tt;
    const float4* B4 = (const float4*)B_p;
    const float4* I4 = (const float4*)I;

    float aJ[3] = {0.f, 0.f, 0.f};
    float a1[3] = {0.f, 0.f, 0.f};
    float a2[9] = {0.f, 0.f, 0.f, 0.f, 0.f, 0.f, 0.f, 0.f, 0.f};

    #pragma unroll
    for (int k = 0; k < 2; ++k) {
        size_t o = cb + threadIdx.x + k * 256;
        float4 j0 = J4[pb + 0 * HW4_ + o];
        float4 j1 = J4[pb + 1 * HW4_ + o];
        float4 j2 = J4[pb + 2 * HW4_ + o];
        #pragma unroll
        for (int c = 0; c < 3; ++c) {
            float4 tv = t4[pb + (size_t)c * HW4_ + o];
            float4 bp = B4[pb + (size_t)c * HW4_ + o];
            float4 iv = I4[pb + (size_t)c * HW4_ + o];
            float4 jc = (c == 0) ? j0 : (c == 1 ? j1 : j2);
#define REDC(m) { \
            float omt = 1.f - tv.m; \
            float r = 1.f / (omt * omt + LAM3); \
            float g = tv.m * omt * r; \
            aJ[c] += jc.m; \
            a1[c] += (LAM3 * bp.m - (jc.m * tv.m - iv.m) * omt) * r; \
            a2[0 * 3 + c] += j0.m * g; \
            a2[1 * 3 + c] += j1.m * g; \
            a2[2 * 3 + c] += j2.m * g; }
            REDC(x) REDC(y) REDC(z) REDC(w)
#undef REDC
        }
    }

    float vals[15];
    #pragma unroll
    for (int c = 0; c < 3; ++c) { vals[c] = aJ[c]; vals[3 + c] = a1[c]; }
    #pragma unroll
    for (int s = 0; s < 9; ++s) vals[6 + s] = a2[s];

    __shared__ float lds[4][15];
    int lane = threadIdx.x & 63, w = threadIdx.x >> 6;
    #pragma unroll
    for (int s = 0; s < 15; ++s) {
        float v = vals[s];
        #pragma unroll
        for (int off = 32; off; off >>= 1) v += __shfl_down(v, off, 64);
        if (lane == 0) lds[w][s] = v;
    }
    __syncthreads();
    if (threadIdx.x < 15) {
        int s = threadIdx.x;
        sums[blk * 16 + s] = lds[0][s] + lds[1][s] + lds[2][s] + lds[3][s];
    }
}

// ---- Pass B: finalize (1 block, 256 threads, 4-way parallel per sum) ----
__global__ __launch_bounds__(256) void kFin(const float* __restrict__ sums,
                     float* __restrict__ alpha, int* __restrict__ idx2,
                     float* __restrict__ BnS,
                     const float* __restrict__ g3p, float* __restrict__ outg3) {
    __shared__ float part[64][4];
    __shared__ float tot[4][15];
    int t = threadIdx.x;
    int g = t >> 2, sub = t & 3;        // 64 groups x 4
    if (g < 60) {
        int b = g / 15, s = g % 15;
        const float* p = sums + (size_t)b * 128 * 16 + s;
        float acc = 0.f;
        #pragma unroll 8
        for (int ch = sub; ch < 128; ch += 4) acc += p[ch * 16];
        part[g][sub] = acc;
    }
    __syncthreads();
    if (t < 60) {
        tot[t / 15][t % 15] = (part[t][0] + part[t][1]) + (part[t][2] + part[t][3]);
    }
    __syncthreads();
    if (t < 4) {
        const float invHW = 1.0f / (float)HW_;
        float m[3] = {tot[t][0] * invHW, tot[t][1] * invHW, tot[t][2] * invHW};
        int r[3];
        #pragma unroll
        for (int i = 0; i < 3; ++i) {
            int ri = 0;
            #pragma unroll
            for (int j = 0; j < 3; ++j)
                if (j != i && (m[j] < m[i] || (m[j] == m[i] && j < i))) ri++;
            r[i] = ri;   // ascending stable rank
        }
        int idx[3]; float ms[3];
        #pragma unroll
        for (int i = 0; i < 3; ++i) { idx[r[i]] = i; ms[r[i]] = m[i]; }
        idx2[t] = idx[2];
        float a[3] = {0.f, 0.f, 0.f};
        a[idx[1]] = ms[2] - ms[1];
        a[idx[0]] = ms[2] - ms[0];
        #pragma unroll
        for (int c = 0; c < 3; ++c) {
            alpha[t * 3 + c] = a[c];
            BnS[t * 3 + c] = (tot[t][3 + c] - a[c] * tot[t][6 + idx[2] * 3 + c]) * invHW;
        }
    }
    if (t == 0) *outg3 = g3p[0];
}

// ---- Pass C: fused elementwise, float4; nontemporal stores for never-re-read outs
__global__ __launch_bounds__(256) void kMain(
    const float* __restrict__ I, const float* __restrict__ t_p,
    const float* __restrict__ Hm, const float* __restrict__ Xm,
    const float* __restrict__ J, const float* __restrict__ u,
    const float* __restrict__ v, const float* __restrict__ Y,
    const float* __restrict__ G,
    const float* __restrict__ g1p, const float* __restrict__ g2p,
    const float* __restrict__ g3p, const float* __restrict__ g4p,
    const float* __restrict__ g5p, const float* __restrict__ t1w,
    const float* __restrict__ alpha, const int* __restrict__ idx2,
    const float* __restrict__ BnS,
    float* __restrict__ out)
{
    int id = blockIdx.x * 256 + threadIdx.x;   // 0 .. 262143
    int b = id >> 16, q = id & (HW4_ - 1);
    float g1 = g1p[0], g2 = g2p[0], g3 = g3p[0], g4 = g4p[0], g5 = g5p[0];
    float wc[3] = {t1w[0], t1w[1], t1w[2]};
    int i2 = idx2[b];
    size_t pb = (size_t)b * (CHW_ / 4);
    const float4* I4p = (const float4*)I;
    const float4* tp4p = (const float4*)t_p;
    const float4* H4p = (const float4*)Hm;
    const float4* X4p = (const float4*)Xm;
    const float4* J4p = (const float4*)J;
    const float4* u4p = (const float4*)u;
    const float4* v4p = (const float4*)v;
    const float4* Y4p = (const float4*)Y;
    const float4* G4p = (const float4*)G;
    float4* o4 = (float4*)out;

    float4 Jl = J4p[pb + (size_t)i2 * HW4_ + q];
    float4 t1 = make_float4(0.f, 0.f, 0.f, 0.f);
    float4 Isv[3]; float Bsv[3];
    const float den2 = LAM2 + g4;
    #pragma unroll
    for (int c = 0; c < 3; ++c) {
        size_t o = pb + (size_t)c * HW4_ + q;
        float4 I4 = I4p[o], tp4 = tp4p[o], H4 = H4p[o], X4 = X4p[o], Jv = J4p[o];
        float al = alpha[b * 3 + c], Bnv = BnS[b * 3 + c];
        float wcc = wc[c];
#define STEP1(m) { \
        float d_ = (Jv.m + al * Jl.m) - Bnv; \
        float tnr_ = (LAM2 * tp4.m + g4 * H4.m - (Bnv - I4.m) * d_ - X4.m) / (d_ * d_ + den2); \
        t1.m += wcc * tnr_; }
        STEP1(x) STEP1(y) STEP1(z) STEP1(w)
#undef STEP1
        Isv[c] = I4; Bsv[c] = Bnv;
    }
    float g345 = g3 + g4 + g5;
    float4 invDen;
    invDen.x = 1.f / (t1.x * t1.x + g345);
    invDen.y = 1.f / (t1.y * t1.y + g345);
    invDen.z = 1.f / (t1.z * t1.z + g345);
    invDen.w = 1.f / (t1.w * t1.w + g345);
    float invDu = 1.f / (g1 + g4), invDv = 1.f / (g2 + g5);
    float4 cu = make_float4(1e30f, 1e30f, 1e30f, 1e30f);
    float4 cv = cu;
    #pragma unroll
    for (int c = 0; c < 3; ++c) {
        size_t o = pb + (size_t)c * HW4_ + q;
        float4 u4 = u4p[o], v4 = v4p[o], Y4 = Y4p[o], G4 = G4p[o];
        float Bnv = Bsv[c];
        float4 Jn4, un4, vn4, Yn4;
#define STEP2(m) { \
        float Jn_ = (t1.m * (Isv[c].m - Bnv * (1.f - t1.m)) + g3 * G4.m + g4 * u4.m \
                     - g5 * v4.m - Y4.m + g5) * invDen.m; \
        float un_ = (g1 * u4.m + g4 * Jn_) * invDu; \
        float vn_ = (g2 * v4.m - g5 * Jn_ + g5) * invDv; \
        Jn4.m = Jn_; un4.m = un_; vn4.m = vn_; \
        Yn4.m = Y4.m + g3 * (Jn_ - G4.m); \
        cu.m = fminf(cu.m, un_); cv.m = fminf(cv.m, vn_); }
        STEP2(x) STEP2(y) STEP2(z) STEP2(w)
#undef STEP2
        nt_store4(make_float4(Bnv, Bnv, Bnv, Bnv), &o4[O_Bn / 4 + o]);
        o4[O_tn / 4 + o] = t1;                                   // re-read by conv
        nt_store4(Jn4, &o4[O_Jn / 4 + o]);
        nt_store4(G4,  &o4[O_G  / 4 + o]);
        nt_store4(un4, &o4[O_un / 4 + o]);
        nt_store4(vn4, &o4[O_vn / 4 + o]);
        nt_store4(Yn4, &o4[O_Yn / 4 + o]);
    }
    // channel-min maps staged in Pn/Qn slots (re-read by kHMin; overwritten by kTail)
    o4[O_Pn / 4 + (size_t)b * HW4_ + q] = cu;
    o4[O_Qn / 4 + (size_t)b * HW4_ + q] = cv;
}

// ---- Pass D: horizontal 35-tap reflect min -> ws scratch ----
__global__ __launch_bounds__(256) void kHMin(const float* __restrict__ out,
                                             float* __restrict__ scr) {
    __shared__ float row[546];   // 512 + 2*17
    int blk = blockIdx.x;                 // 0..4095
    int tensor = blk >> 11;               // 0: u, 1: v
    int rem = blk & 2047;
    int b = rem >> 9, y = rem & 511;
    const float* src = out + (tensor ? O_Qn : O_Pn) + b * HW_ + y * W_;
    float* dst = scr + (size_t)(tensor * 4 + b) * HW_ + y * W_;
    for (int j = threadIdx.x; j < 546; j += 256) {
        int xx = j - 17;
        xx = xx < 0 ? -xx : (xx >= W_ ? 2 * W_ - 2 - xx : xx);
        row[j] = src[xx];
    }
    __syncthreads();
    for (int x = threadIdx.x; x < W_; x += 256) {
        float m = row[x];
        #pragma unroll
        for (int k = 1; k < 35; ++k) m = fminf(m, row[x + k]);
        dst[x] = m;
    }
}

// ---- Pass E (fused tail): blocks [0,8192) = vertical min + soft-thresh;
//      blocks [8192,12288) = 3x3 conv + X update. Independent regions.
__global__ __launch_bounds__(256) void kTail(const float* __restrict__ scr,
                                             const float* __restrict__ Xm,
                                             const float* __restrict__ hw,
                                             const float* __restrict__ g1p,
                                             const float* __restrict__ g4p,
                                             float* __restrict__ out) {
    __shared__ float w[81];
    if (blockIdx.x < 8192) {
        // ---- vertical 35-tap reflect min + soft threshold -> Pn/Qn ----
        int tensor = blockIdx.x >> 12;
        int lid = ((blockIdx.x & 4095) << 8) + threadIdx.x;
        int b = lid >> 18, p = lid & (HW_ - 1);
        int y = p >> 9, x = p & 511;
        const float* R = scr + (size_t)(tensor * 4 + b) * HW_;
        float m = 1e30f;
        #pragma unroll
        for (int k = 0; k < 35; ++k) {
            int yy = y + k - 17;
            yy = yy < 0 ? -yy : (yy >= H_ ? 2 * H_ - 2 - yy : yy);
            m = fminf(m, R[yy * W_ + x]);
        }
        float lam = 1.0f / g1p[0];        // lam4/g1 == lam5/g1 == 1/g1
        float s = (m > 0.f) ? 1.f : (m < 0.f ? -1.f : 0.f);
        float r = s * fmaxf(fabsf(m) - lam, 0.f);
        __builtin_nontemporal_store(r, &out[(tensor ? O_Qn : O_Pn) + b * HW_ + p]);
    } else {
        // ---- 3x3 zero-pad conv -> Hn, Xn ----
        if (threadIdx.x < 81) w[threadIdx.x] = hw[threadIdx.x];
        __syncthreads();
        int id = (blockIdx.x - 8192) * 256 + threadIdx.x;
        int b = id >> 18, p = id & (HW_ - 1);
        int y = p >> 9, x = p & 511;
        float g4 = g4p[0], ig4 = 1.f / g4;
        const float* tn = out + O_tn + (size_t)b * CHW_;   // channel 0 (tn channel-const)
        float acc0 = 0.f, acc1 = 0.f, acc2 = 0.f;
        #pragma unroll
        for (int ky = 0; ky < 3; ++ky) {
            int yy = y + ky - 1;
            if (yy < 0 || yy >= H_) continue;
            #pragma unroll
            for (int kx = 0; kx < 3; ++kx) {
                int xx = x + kx - 1;
                if (xx < 0 || xx >= W_) continue;
                int pp = yy * W_ + xx;
                float t1v = tn[pp];
                #pragma unroll
                for (int i = 0; i < 3; ++i) {
                    float Av = t1v + Xm[(size_t)(b * 3 + i) * HW_ + pp] * ig4;
                    int kk = i * 9 + ky * 3 + kx;
                    acc0 += w[kk] * Av;
                    acc1 += w[27 + kk] * Av;
                    acc2 += w[54 + kk] * Av;
                }
            }
        }
        float t1c = tn[p];
        float acc[3] = {acc0, acc1, acc2};
        #pragma unroll
        for (int o = 0; o < 3; ++o) {
            size_t oo = (size_t)(b * 3 + o) * HW_ + p;
            __builtin_nontemporal_store(acc[o], &out[O_Hn + oo]);
            __builtin_nontemporal_store(Xm[oo] + g4 * (t1c - acc[o]), &out[O_Xn + oo]);
        }
    }
}

extern "C" void kernel_launch(void* const* d_in, const int* in_sizes, int n_in,
                              void* d_out, int out_size, void* d_ws, size_t ws_size,
                              hipStream_t stream) {
    (void)in_sizes; (void)n_in; (void)out_size; (void)ws_size;
    const float* I   = (const float*)d_in[0];
    const float* t_p = (const float*)d_in[1];
    const float* B_p = (const float*)d_in[2];
    const float* tt  = (const float*)d_in[4];
    const float* J   = (const float*)d_in[5];
    const float* G   = (const float*)d_in[6];
    const float* Hm  = (const float*)d_in[7];
    const float* u   = (const float*)d_in[10];
    const float* v   = (const float*)d_in[11];
    const float* X   = (const float*)d_in[12];
    const float* Y   = (const float*)d_in[13];
    const float* g1  = (const float*)d_in[14];
    const float* g2  = (const float*)d_in[15];
    const float* g3  = (const float*)d_in[16];
    const float* g4  = (const float*)d_in[17];
    const float* g5  = (const float*)d_in[18];
    const float* t1w = (const float*)d_in[19];
    const float* hw  = (const float*)d_in[20];
    float* out = (float*)d_out;
    float* ws  = (float*)d_ws;

    float* sums  = ws + WS_SUMS;
    float* alpha = ws + WS_ALPHA;
    int*   idx2  = (int*)(ws + WS_IDX2);
    float* BnS   = ws + WS_BNS;
    float* scr   = ws + WS_SCR;

    kRed<<<512, 256, 0, stream>>>(J, tt, B_p, I, sums);
    kFin<<<1, 256, 0, stream>>>(sums, alpha, idx2, BnS, g3, out + O_g3);
    kMain<<<1024, 256, 0, stream>>>(I, t_p, Hm, X, J, u, v, Y, G,
                                    g1, g2, g3, g4, g5, t1w, alpha, idx2, BnS, out);
    kHMin<<<4096, 256, 0, stream>>>(out, scr);
    kTail<<<12288, 256, 0, stream>>>(scr, X, hw, g1, g4, out);
}

// Round 5
// 310.612 us; speedup vs baseline: 1.0661x; 1.0389x over previous
//
#include <hip/hip_runtime.h>
#include <math.h>

// Problem geometry
#define W_ 512
#define H_ 512
#define HW_ 262144          // 512*512 = 2^18
#define HW4_ 65536          // HW/4 (float4 units)
#define CHW_ 786432         // 3*HW

// d_out offsets (floats), return order:
// (Bn, tn, Jn, G, Hn, Pn, Qn, un, vn, Xn, Yn, gamma_3)
#define O_Bn 0
#define O_tn 3145728
#define O_Jn 6291456
#define O_G  9437184
#define O_Hn 12582912
#define O_Pn 15728640
#define O_Qn 16777216
#define O_un 17825792
#define O_vn 20971520
#define O_Xn 24117248
#define O_Yn 27262976
#define O_g3 30408704

#define LAM2 0.7f
#define LAM3 0.3f

// ws layout (floats)
#define WS_SUMS   0        // 512*16 = 8192
#define WS_ALPHA  8192     // 12
#define WS_IDX2   8204     // 4 (ints)
#define WS_BNS    8208     // 12
#define WS_SCR    16384    // 2*4*HW = 2097152 floats (H-min scratch)

// native clang vector for nontemporal 16B stores (HIP float4 is a class type
// that __builtin_nontemporal_store rejects)
typedef float nfloat4 __attribute__((ext_vector_type(4)));

__device__ __forceinline__ void nt_store4(float4 v, float4* p) {
    nfloat4 nv; nv.x = v.x; nv.y = v.y; nv.z = v.z; nv.w = v.w;
    __builtin_nontemporal_store(nv, (nfloat4*)p);
}

// ---- Pass A: ONE fused reduction over I, t, B_p, J.
// Per batch b, 15 sums: sJ[c] (3), S1[c] (3), S2[l][c] (9):
//   den = (1-t_c)^2 + lam3
//   S1[c]    = sum[ (lam3*B_p - (J_c*t_c - I_c)*(1-t_c)) / den ]
//   S2[l][c] = sum[ J_l * t_c*(1-t_c) / den ]
// Bn_mean[b,c] = (S1[c] - alpha_c * S2[idx2][c]) / HW  (alpha applied in kFin)
__global__ __launch_bounds__(256) void kRed(const float* __restrict__ J,
                                            const float* __restrict__ tt,
                                            const float* __restrict__ B_p,
                                            const float* __restrict__ I,
                                            float* __restrict__ sums) {
    int blk = blockIdx.x;              // 0..511
    int b = blk >> 7, chunk = blk & 127;
    size_t pb = (size_t)b * (CHW_ / 4);
    size_t cb = (size_t)chunk * 512;
    const float4* J4 = (const float4*)J;
    const float4* t4 = (const float4*)tt;
    const float4* B4 = (const float4*)B_p;
    const float4* I4 = (const float4*)I;

    float aJ[3] = {0.f, 0.f, 0.f};
    float a1[3] = {0.f, 0.f, 0.f};
    float a2[9] = {0.f, 0.f, 0.f, 0.f, 0.f, 0.f, 0.f, 0.f, 0.f};

    #pragma unroll
    for (int k = 0; k < 2; ++k) {
        size_t o = cb + threadIdx.x + k * 256;
        float4 j0 = J4[pb + 0 * HW4_ + o];
        float4 j1 = J4[pb + 1 * HW4_ + o];
        float4 j2 = J4[pb + 2 * HW4_ + o];
        #pragma unroll
        for (int c = 0; c < 3; ++c) {
            float4 tv = t4[pb + (size_t)c * HW4_ + o];
            float4 bp = B4[pb + (size_t)c * HW4_ + o];
            float4 iv = I4[pb + (size_t)c * HW4_ + o];
            float4 jc = (c == 0) ? j0 : (c == 1 ? j1 : j2);
#define REDC(m) { \
            float omt = 1.f - tv.m; \
            float r = 1.f / (omt * omt + LAM3); \
            float g = tv.m * omt * r; \
            aJ[c] += jc.m; \
            a1[c] += (LAM3 * bp.m - (jc.m * tv.m - iv.m) * omt) * r; \
            a2[0 * 3 + c] += j0.m * g; \
            a2[1 * 3 + c] += j1.m * g; \
            a2[2 * 3 + c] += j2.m * g; }
            REDC(x) REDC(y) REDC(z) REDC(w)
#undef REDC
        }
    }

    float vals[15];
    #pragma unroll
    for (int c = 0; c < 3; ++c) { vals[c] = aJ[c]; vals[3 + c] = a1[c]; }
    #pragma unroll
    for (int s = 0; s < 9; ++s) vals[6 + s] = a2[s];

    __shared__ float lds[4][15];
    int lane = threadIdx.x & 63, w = threadIdx.x >> 6;
    #pragma unroll
    for (int s = 0; s < 15; ++s) {
        float v = vals[s];
        #pragma unroll
        for (int off = 32; off; off >>= 1) v += __shfl_down(v, off, 64);
        if (lane == 0) lds[w][s] = v;
    }
    __syncthreads();
    if (threadIdx.x < 15) {
        int s = threadIdx.x;
        sums[blk * 16 + s] = lds[0][s] + lds[1][s] + lds[2][s] + lds[3][s];
    }
}

// ---- Pass B: finalize (1 block, 256 threads, 4-way parallel per sum) ----
__global__ __launch_bounds__(256) void kFin(const float* __restrict__ sums,
                     float* __restrict__ alpha, int* __restrict__ idx2,
                     float* __restrict__ BnS,
                     const float* __restrict__ g3p, float* __restrict__ outg3) {
    __shared__ float part[64][4];
    __shared__ float tot[4][15];
    int t = threadIdx.x;
    int g = t >> 2, sub = t & 3;        // 64 groups x 4
    if (g < 60) {
        int b = g / 15, s = g % 15;
        const float* p = sums + (size_t)b * 128 * 16 + s;
        float acc = 0.f;
        #pragma unroll 8
        for (int ch = sub; ch < 128; ch += 4) acc += p[ch * 16];
        part[g][sub] = acc;
    }
    __syncthreads();
    if (t < 60) {
        tot[t / 15][t % 15] = (part[t][0] + part[t][1]) + (part[t][2] + part[t][3]);
    }
    __syncthreads();
    if (t < 4) {
        const float invHW = 1.0f / (float)HW_;
        float m[3] = {tot[t][0] * invHW, tot[t][1] * invHW, tot[t][2] * invHW};
        int r[3];
        #pragma unroll
        for (int i = 0; i < 3; ++i) {
            int ri = 0;
            #pragma unroll
            for (int j = 0; j < 3; ++j)
                if (j != i && (m[j] < m[i] || (m[j] == m[i] && j < i))) ri++;
            r[i] = ri;   // ascending stable rank
        }
        int idx[3]; float ms[3];
        #pragma unroll
        for (int i = 0; i < 3; ++i) { idx[r[i]] = i; ms[r[i]] = m[i]; }
        idx2[t] = idx[2];
        float a[3] = {0.f, 0.f, 0.f};
        a[idx[1]] = ms[2] - ms[1];
        a[idx[0]] = ms[2] - ms[0];
        #pragma unroll
        for (int c = 0; c < 3; ++c) {
            alpha[t * 3 + c] = a[c];
            BnS[t * 3 + c] = (tot[t][3 + c] - a[c] * tot[t][6 + idx[2] * 3 + c]) * invHW;
        }
    }
    if (t == 0) *outg3 = g3p[0];
}

// ---- Pass C: fused elementwise + horizontal 35-tap reflect-min.
// Each block = 2 complete rows (1024 px) of one batch; h-min is row-local.
__global__ __launch_bounds__(256) void kMain(
    const float* __restrict__ I, const float* __restrict__ t_p,
    const float* __restrict__ Hm, const float* __restrict__ Xm,
    const float* __restrict__ J, const float* __restrict__ u,
    const float* __restrict__ v, const float* __restrict__ Y,
    const float* __restrict__ G,
    const float* __restrict__ g1p, const float* __restrict__ g2p,
    const float* __restrict__ g3p, const float* __restrict__ g4p,
    const float* __restrict__ g5p, const float* __restrict__ t1w,
    const float* __restrict__ alpha, const int* __restrict__ idx2,
    const float* __restrict__ BnS,
    float* __restrict__ out, float* __restrict__ scr)
{
    // pad rows: [tensor u/v][row 0/1][560]; main data at [17, 529)
    __shared__ float pad[2][2][560];

    int id = blockIdx.x * 256 + threadIdx.x;   // float4 index, 0 .. 262143
    int b = id >> 16, q = id & (HW4_ - 1);
    float g1 = g1p[0], g2 = g2p[0], g3 = g3p[0], g4 = g4p[0], g5 = g5p[0];
    float wc[3] = {t1w[0], t1w[1], t1w[2]};
    int i2 = idx2[b];
    size_t pb = (size_t)b * (CHW_ / 4);
    const float4* I4p = (const float4*)I;
    const float4* tp4p = (const float4*)t_p;
    const float4* H4p = (const float4*)Hm;
    const float4* X4p = (const float4*)Xm;
    const float4* J4p = (const float4*)J;
    const float4* u4p = (const float4*)u;
    const float4* v4p = (const float4*)v;
    const float4* Y4p = (const float4*)Y;
    const float4* G4p = (const float4*)G;
    float4* o4 = (float4*)out;

    float4 Jl = J4p[pb + (size_t)i2 * HW4_ + q];
    float4 t1 = make_float4(0.f, 0.f, 0.f, 0.f);
    float4 Isv[3]; float Bsv[3];
    const float den2 = LAM2 + g4;
    #pragma unroll
    for (int c = 0; c < 3; ++c) {
        size_t o = pb + (size_t)c * HW4_ + q;
        float4 I4 = I4p[o], tp4 = tp4p[o], H4 = H4p[o], X4 = X4p[o], Jv = J4p[o];
        float al = alpha[b * 3 + c], Bnv = BnS[b * 3 + c];
        float wcc = wc[c];
#define STEP1(m) { \
        float d_ = (Jv.m + al * Jl.m) - Bnv; \
        float tnr_ = (LAM2 * tp4.m + g4 * H4.m - (Bnv - I4.m) * d_ - X4.m) / (d_ * d_ + den2); \
        t1.m += wcc * tnr_; }
        STEP1(x) STEP1(y) STEP1(z) STEP1(w)
#undef STEP1
        Isv[c] = I4; Bsv[c] = Bnv;
    }
    float g345 = g3 + g4 + g5;
    float4 invDen;
    invDen.x = 1.f / (t1.x * t1.x + g345);
    invDen.y = 1.f / (t1.y * t1.y + g345);
    invDen.z = 1.f / (t1.z * t1.z + g345);
    invDen.w = 1.f / (t1.w * t1.w + g345);
    float invDu = 1.f / (g1 + g4), invDv = 1.f / (g2 + g5);
    float4 cu = make_float4(1e30f, 1e30f, 1e30f, 1e30f);
    float4 cv = cu;
    #pragma unroll
    for (int c = 0; c < 3; ++c) {
        size_t o = pb + (size_t)c * HW4_ + q;
        float4 u4 = u4p[o], v4 = v4p[o], Y4 = Y4p[o], G4 = G4p[o];
        float Bnv = Bsv[c];
        float4 Jn4, un4, vn4, Yn4;
#define STEP2(m) { \
        float Jn_ = (t1.m * (Isv[c].m - Bnv * (1.f - t1.m)) + g3 * G4.m + g4 * u4.m \
                     - g5 * v4.m - Y4.m + g5) * invDen.m; \
        float un_ = (g1 * u4.m + g4 * Jn_) * invDu; \
        float vn_ = (g2 * v4.m - g5 * Jn_ + g5) * invDv; \
        Jn4.m = Jn_; un4.m = un_; vn4.m = vn_; \
        Yn4.m = Y4.m + g3 * (Jn_ - G4.m); \
        cu.m = fminf(cu.m, un_); cv.m = fminf(cv.m, vn_); }
        STEP2(x) STEP2(y) STEP2(z) STEP2(w)
#undef STEP2
        nt_store4(make_float4(Bnv, Bnv, Bnv, Bnv), &o4[O_Bn / 4 + o]);
        o4[O_tn / 4 + o] = t1;                                   // re-read by conv
        nt_store4(Jn4, &o4[O_Jn / 4 + o]);
        nt_store4(G4,  &o4[O_G  / 4 + o]);
        nt_store4(un4, &o4[O_un / 4 + o]);
        nt_store4(vn4, &o4[O_vn / 4 + o]);
        nt_store4(Yn4, &o4[O_Yn / 4 + o]);
    }

    // ---- fused horizontal 35-tap reflect min on cu/cv -> scr ----
    int t = threadIdx.x;
    int rrow = t >> 7;                 // 0..1
    int x0 = (t & 127) * 4;            // px base within row
    pad[0][rrow][17 + x0 + 0] = cu.x;
    pad[0][rrow][17 + x0 + 1] = cu.y;
    pad[0][rrow][17 + x0 + 2] = cu.z;
    pad[0][rrow][17 + x0 + 3] = cu.w;
    pad[1][rrow][17 + x0 + 0] = cv.x;
    pad[1][rrow][17 + x0 + 1] = cv.y;
    pad[1][rrow][17 + x0 + 2] = cv.z;
    pad[1][rrow][17 + x0 + 3] = cv.w;
    __syncthreads();
    if (t < 136) {                      // reflect edge fill: 4 rows x 34 cells
        int which = t / 34, e = t % 34;
        int tens = which >> 1, rw = which & 1;
        int j   = (e < 17) ? e : (529 + (e - 17));
        int src = (e < 17) ? (34 - j) : (1056 - j);
        pad[tens][rw][j] = pad[tens][rw][src];
    }
    __syncthreads();

    int y0b = (blockIdx.x & 255) * 2;   // first row of this block
    int yg = y0b + rrow;
    #pragma unroll
    for (int tens = 0; tens < 2; ++tens) {
        const float* rowp = &pad[tens][rrow][0];
        const float4* rp4 = (const float4*)(rowp + x0);   // 16B-aligned
        float4 qv = rp4[0];
        float a0 = qv.x, a1 = qv.y, a2 = qv.z;
        float mc = qv.w;
        #pragma unroll
        for (int i = 1; i < 8; ++i) {
            qv = rp4[i];
            mc = fminf(mc, fminf(fminf(qv.x, qv.y), fminf(qv.z, qv.w)));
        }
        qv = rp4[8];
        mc = fminf(mc, fminf(qv.x, fminf(qv.y, qv.z)));
        float a35 = qv.w;
        qv = rp4[9];
        float a36 = qv.x, a37 = qv.y;
        float4 r;
        r.x = fminf(fminf(a0, a1), fminf(a2, mc));
        r.y = fminf(fminf(a1, a2), fminf(mc, a35));
        r.z = fminf(fminf(a2, mc), fminf(a35, a36));
        r.w = fminf(fminf(mc, a35), fminf(a36, a37));
        *(float4*)(scr + (size_t)(tens * 4 + b) * HW_ + yg * W_ + x0) = r;
    }
}

// ---- Pass D (fused tail): blocks [0,2048) = vertical min + soft-thresh (float4);
//      blocks [2048,3072) = LDS-staged 3x3 conv + X update.
__global__ __launch_bounds__(256) void kTail(const float* __restrict__ scr,
                                             const float* __restrict__ hw,
                                             const float* __restrict__ g1p,
                                             const float* __restrict__ g4p,
                                             float* __restrict__ out) {
    // conv staging: A[i] = t1 + X_i/g4, rows y0-1..y0+2, main at [4,516), stride 528
    __shared__ float A_lds[3][4][528];
    __shared__ float wsh[81];
    int t = threadIdx.x;

    if (blockIdx.x < 2048) {
        // ---- vertical 35-tap reflect min + soft threshold -> Pn/Qn ----
        int tensor = blockIdx.x >> 10;
        int lid = ((blockIdx.x & 1023) << 8) + t;
        int b = lid >> 16, qq = lid & (HW4_ - 1);
        int y = qq >> 7, xq = (qq & 127) << 2;
        const float* R = scr + (size_t)(tensor * 4 + b) * HW_;
        float4 m = make_float4(1e30f, 1e30f, 1e30f, 1e30f);
        #pragma unroll
        for (int k = 0; k < 35; ++k) {
            int yy = y + k - 17;
            yy = yy < 0 ? -yy : (yy >= H_ ? 2 * H_ - 2 - yy : yy);
            float4 r4 = *(const float4*)(R + yy * W_ + xq);
            m.x = fminf(m.x, r4.x); m.y = fminf(m.y, r4.y);
            m.z = fminf(m.z, r4.z); m.w = fminf(m.w, r4.w);
        }
        float lam = 1.0f / g1p[0];        // lam4/g1 == lam5/g1 == 1/g1
        float4 r;
#define SOFT(m_, r_) { float s = (m_ > 0.f) ? 1.f : (m_ < 0.f ? -1.f : 0.f); \
                       r_ = s * fmaxf(fabsf(m_) - lam, 0.f); }
        SOFT(m.x, r.x) SOFT(m.y, r.y) SOFT(m.z, r.z) SOFT(m.w, r.w)
#undef SOFT
        nt_store4(r, (float4*)(out + (tensor ? O_Qn : O_Pn) + b * HW_ + y * W_ + xq));
    } else {
        // ---- 3x3 zero-pad conv on A = tn + X/g4 -> Hn; Xn = g4*(A_c - Hn) ----
        int cblk = blockIdx.x - 2048;        // 0..1023
        int b = cblk >> 8;
        int y0 = (cblk & 255) * 2;
        float g4 = g4p[0], ig4 = 1.f / g4;
        const float* tn0 = out + O_tn + (size_t)b * CHW_;   // tn channel 0 (channel-const)
        const float* Xb  = out + O_Xn;                      // not used; placeholder
        (void)Xb;
        if (t < 81) wsh[t] = hw[t];
        // stage A: 3 ch x 4 rows x 512 = 1536 float4-groups
        #pragma unroll
        for (int k = 0; k < 6; ++k) {
            int g = t + 256 * k;
            int i = g >> 9, r = (g >> 7) & 3, xq = (g & 127) << 2;
            int yy = y0 - 1 + r;
            float4 A4;
            if (yy >= 0 && yy < H_) {
                const float* Xrow = /* X input */ nullptr;  // set below via out? no
                (void)Xrow;
                A4 = make_float4(0.f, 0.f, 0.f, 0.f);
            }
            // (filled in below — see launcher passing X via scr2)
            (void)A4; (void)i; (void)r; (void)xq; (void)yy;
        }
        // NOTE: restructured below with X pointer parameter.
    }
}

// Separate conv implementation with the X input pointer (kept out of kTail to
// keep parameter lists clean): see kTail2.
__global__ __launch_bounds__(256) void kTail2(const float* __restrict__ scr,
                                              const float* __restrict__ Xm,
                                              const float* __restrict__ hw,
                                              const float* __restrict__ g1p,
                                              const float* __restrict__ g4p,
                                              float* __restrict__ out) {
    __shared__ float A_lds[3][4][528];
    __shared__ float wsh[81];
    int t = threadIdx.x;

    if (blockIdx.x < 2048) {
        int tensor = blockIdx.x >> 10;
        int lid = ((blockIdx.x & 1023) << 8) + t;
        int b = lid >> 16, qq = lid & (HW4_ - 1);
        int y = qq >> 7, xq = (qq & 127) << 2;
        const float* R = scr + (size_t)(tensor * 4 + b) * HW_;
        float4 m = make_float4(1e30f, 1e30f, 1e30f, 1e30f);
        #pragma unroll
        for (int k = 0; k < 35; ++k) {
            int yy = y + k - 17;
            yy = yy < 0 ? -yy : (yy >= H_ ? 2 * H_ - 2 - yy : yy);
            float4 r4 = *(const float4*)(R + yy * W_ + xq);
            m.x = fminf(m.x, r4.x); m.y = fminf(m.y, r4.y);
            m.z = fminf(m.z, r4.z); m.w = fminf(m.w, r4.w);
        }
        float lam = 1.0f / g1p[0];
        float4 r;
#define SOFT(m_, r_) { float s = (m_ > 0.f) ? 1.f : (m_ < 0.f ? -1.f : 0.f); \
                       r_ = s * fmaxf(fabsf(m_) - lam, 0.f); }
        SOFT(m.x, r.x) SOFT(m.y, r.y) SOFT(m.z, r.z) SOFT(m.w, r.w)
#undef SOFT
        nt_store4(r, (float4*)(out + (tensor ? O_Qn : O_Pn) + b * HW_ + y * W_ + xq));
    } else {
        int cblk = blockIdx.x - 2048;        // 0..1023
        int b = cblk >> 8;
        int y0 = (cblk & 255) * 2;
        float g4 = g4p[0], ig4 = 1.f / g4;
        const float* tn0 = out + O_tn + (size_t)b * CHW_;
        if (t < 81) wsh[t] = hw[t];
        // stage A[i][r][4+x] = tn0[yy,x] + X[i][yy,x]/g4 (zero rows outside)
        #pragma unroll
        for (int k = 0; k < 6; ++k) {
            int g = t + 256 * k;
            int i = g >> 9, r = (g >> 7) & 3, xq = (g & 127) << 2;
            int yy = y0 - 1 + r;
            float4 A4 = make_float4(0.f, 0.f, 0.f, 0.f);
            if (yy >= 0 && yy < H_) {
                float4 tn4 = *(const float4*)(tn0 + yy * W_ + xq);
                float4 X4  = *(const float4*)(Xm + (size_t)(b * 3 + i) * HW_ + yy * W_ + xq);
                A4.x = tn4.x + X4.x * ig4; A4.y = tn4.y + X4.y * ig4;
                A4.z = tn4.z + X4.z * ig4; A4.w = tn4.w + X4.w * ig4;
            }
            *(float4*)(&A_lds[i][r][4 + xq]) = A4;
        }
        if (t < 24) {                        // zero x-halo cells [3] and [516]
            int pair = t >> 1, side = t & 1;
            A_lds[pair >> 2][pair & 3][side ? 516 : 3] = 0.f;
        }
        __syncthreads();

        int tl = t & 127, r_out = t >> 7;    // 4 px at x = tl + 128j, row y0+r_out
        float acc[3][4] = {{0.f,0.f,0.f,0.f},{0.f,0.f,0.f,0.f},{0.f,0.f,0.f,0.f}};
        #pragma unroll
        for (int i = 0; i < 3; ++i) {
            #pragma unroll
            for (int ky = 0; ky < 3; ++ky) {
                const float* Ar = &A_lds[i][r_out + ky][0];
                const float* wp0 = &wsh[0 * 27 + i * 9 + ky * 3];
                const float* wp1 = &wsh[1 * 27 + i * 9 + ky * 3];
                const float* wp2 = &wsh[2 * 27 + i * 9 + ky * 3];
                float w00 = wp0[0], w01 = wp0[1], w02 = wp0[2];
                float w10 = wp1[0], w11 = wp1[1], w12 = wp1[2];
                float w20 = wp2[0], w21 = wp2[1], w22 = wp2[2];
                #pragma unroll
                for (int j = 0; j < 4; ++j) {
                    int x = tl + 128 * j;
                    float am = Ar[3 + x], a0 = Ar[4 + x], ap = Ar[5 + x];
                    acc[0][j] += w00 * am + w01 * a0 + w02 * ap;
                    acc[1][j] += w10 * am + w11 * a0 + w12 * ap;
                    acc[2][j] += w20 * am + w21 * a0 + w22 * ap;
                }
            }
        }
        int yg = y0 + r_out;
        #pragma unroll
        for (int o = 0; o < 3; ++o) {
            #pragma unroll
            for (int j = 0; j < 4; ++j) {
                int x = tl + 128 * j;
                size_t oo = (size_t)(b * 3 + o) * HW_ + yg * W_ + x;
                float hn = acc[o][j];
                float Ac = A_lds[o][r_out + 1][4 + x];
                __builtin_nontemporal_store(hn, &out[O_Hn + oo]);
                __builtin_nontemporal_store(g4 * (Ac - hn), &out[O_Xn + oo]);
            }
        }
    }
}

extern "C" void kernel_launch(void* const* d_in, const int* in_sizes, int n_in,
                              void* d_out, int out_size, void* d_ws, size_t ws_size,
                              hipStream_t stream) {
    (void)in_sizes; (void)n_in; (void)out_size; (void)ws_size;
    const float* I   = (const float*)d_in[0];
    const float* t_p = (const float*)d_in[1];
    const float* B_p = (const float*)d_in[2];
    const float* tt  = (const float*)d_in[4];
    const float* J   = (const float*)d_in[5];
    const float* G   = (const float*)d_in[6];
    const float* Hm  = (const float*)d_in[7];
    const float* u   = (const float*)d_in[10];
    const float* v   = (const float*)d_in[11];
    const float* X   = (const float*)d_in[12];
    const float* Y   = (const float*)d_in[13];
    const float* g1  = (const float*)d_in[14];
    const float* g2  = (const float*)d_in[15];
    const float* g3  = (const float*)d_in[16];
    const float* g4  = (const float*)d_in[17];
    const float* g5  = (const float*)d_in[18];
    const float* t1w = (const float*)d_in[19];
    const float* hw  = (const float*)d_in[20];
    float* out = (float*)d_out;
    float* ws  = (float*)d_ws;

    float* sums  = ws + WS_SUMS;
    float* alpha = ws + WS_ALPHA;
    int*   idx2  = (int*)(ws + WS_IDX2);
    float* BnS   = ws + WS_BNS;
    float* scr   = ws + WS_SCR;

    kRed<<<512, 256, 0, stream>>>(J, tt, B_p, I, sums);
    kFin<<<1, 256, 0, stream>>>(sums, alpha, idx2, BnS, g3, out + O_g3);
    kMain<<<1024, 256, 0, stream>>>(I, t_p, Hm, X, J, u, v, Y, G,
                                    g1, g2, g3, g4, g5, t1w, alpha, idx2, BnS,
                                    out, scr);
    kTail2<<<3072, 256, 0, stream>>>(scr, X, hw, g1, g4, out);
}

// Round 6
// 308.714 us; speedup vs baseline: 1.0726x; 1.0061x over previous
//
#include <hip/hip_runtime.h>
#include <math.h>

// Problem geometry
#define W_ 512
#define H_ 512
#define HW_ 262144          // 512*512 = 2^18
#define HW4_ 65536          // HW/4 (float4 units)
#define CHW_ 786432         // 3*HW

// d_out offsets (floats), return order:
// (Bn, tn, Jn, G, Hn, Pn, Qn, un, vn, Xn, Yn, gamma_3)
#define O_Bn 0
#define O_tn 3145728
#define O_Jn 6291456
#define O_G  9437184
#define O_Hn 12582912
#define O_Pn 15728640
#define O_Qn 16777216
#define O_un 17825792
#define O_vn 20971520
#define O_Xn 24117248
#define O_Yn 27262976
#define O_g3 30408704

#define LAM2 0.7f
#define LAM3 0.3f

// ws layout (floats)
#define WS_ACC    0        // 64 floats, zeroed by hipMemsetAsync (60 used: [b*15+s])
#define WS_SCR    16384    // 2*4*HW floats (H-min scratch)

// native clang vector for nontemporal 16B stores (HIP float4 is a class type
// that __builtin_nontemporal_store rejects)
typedef float nfloat4 __attribute__((ext_vector_type(4)));

__device__ __forceinline__ void nt_store4(float4 v, float4* p) {
    nfloat4 nv; nv.x = v.x; nv.y = v.y; nv.z = v.z; nv.w = v.w;
    __builtin_nontemporal_store(nv, (nfloat4*)p);
}

// ---- Pass A: fused reduction over I, t, B_p, J -> 60 atomic accumulators.
// Per batch b, 15 sums: sJ[c] (3), S1[c] (3), S2[l][c] (9):
//   den = (1-t_c)^2 + lam3
//   S1[c]    = sum[ (lam3*B_p - (J_c*t_c - I_c)*(1-t_c)) / den ]
//   S2[l][c] = sum[ J_l * t_c*(1-t_c) / den ]
// Kernel boundary = barrier: kMain's prologue does the finalize per block.
__global__ __launch_bounds__(256) void kRed(const float* __restrict__ J,
                                            const float* __restrict__ tt,
                                            const float* __restrict__ B_p,
                                            const float* __restrict__ I,
                                            float* __restrict__ acc) {
    int blk = blockIdx.x;              // 0..511
    int b = blk >> 7, chunk = blk & 127;
    size_t pb = (size_t)b * (CHW_ / 4);
    size_t cb = (size_t)chunk * 512;
    const float4* J4 = (const float4*)J;
    const float4* t4 = (const float4*)tt;
    const float4* B4 = (const float4*)B_p;
    const float4* I4 = (const float4*)I;

    float aJ[3] = {0.f, 0.f, 0.f};
    float a1[3] = {0.f, 0.f, 0.f};
    float a2[9] = {0.f, 0.f, 0.f, 0.f, 0.f, 0.f, 0.f, 0.f, 0.f};

    #pragma unroll
    for (int k = 0; k < 2; ++k) {
        size_t o = cb + threadIdx.x + k * 256;
        float4 j0 = J4[pb + 0 * HW4_ + o];
        float4 j1 = J4[pb + 1 * HW4_ + o];
        float4 j2 = J4[pb + 2 * HW4_ + o];
        #pragma unroll
        for (int c = 0; c < 3; ++c) {
            float4 tv = t4[pb + (size_t)c * HW4_ + o];
            float4 bp = B4[pb + (size_t)c * HW4_ + o];
            float4 iv = I4[pb + (size_t)c * HW4_ + o];
            float4 jc = (c == 0) ? j0 : (c == 1 ? j1 : j2);
#define REDC(m) { \
            float omt = 1.f - tv.m; \
            float r = 1.f / (omt * omt + LAM3); \
            float g = tv.m * omt * r; \
            aJ[c] += jc.m; \
            a1[c] += (LAM3 * bp.m - (jc.m * tv.m - iv.m) * omt) * r; \
            a2[0 * 3 + c] += j0.m * g; \
            a2[1 * 3 + c] += j1.m * g; \
            a2[2 * 3 + c] += j2.m * g; }
            REDC(x) REDC(y) REDC(z) REDC(w)
#undef REDC
        }
    }

    float vals[15];
    #pragma unroll
    for (int c = 0; c < 3; ++c) { vals[c] = aJ[c]; vals[3 + c] = a1[c]; }
    #pragma unroll
    for (int s = 0; s < 9; ++s) vals[6 + s] = a2[s];

    __shared__ float lds[4][15];
    int lane = threadIdx.x & 63, w = threadIdx.x >> 6;
    #pragma unroll
    for (int s = 0; s < 15; ++s) {
        float v = vals[s];
        #pragma unroll
        for (int off = 32; off; off >>= 1) v += __shfl_down(v, off, 64);
        if (lane == 0) lds[w][s] = v;
    }
    __syncthreads();
    if (threadIdx.x < 15) {
        int s = threadIdx.x;
        atomicAdd(&acc[b * 15 + s],
                  (lds[0][s] + lds[1][s]) + (lds[2][s] + lds[3][s]));
    }
}

// ---- Pass B: fused elementwise + finalize-prologue + horizontal 35-tap
// reflect-min + 3x3 zero-pad conv (halo-row t1 recompute). Block = 2 rows.
__global__ __launch_bounds__(256) void kMain(
    const float* __restrict__ I, const float* __restrict__ t_p,
    const float* __restrict__ Hm, const float* __restrict__ Xm,
    const float* __restrict__ J, const float* __restrict__ u,
    const float* __restrict__ v, const float* __restrict__ Y,
    const float* __restrict__ G,
    const float* __restrict__ g1p, const float* __restrict__ g2p,
    const float* __restrict__ g3p, const float* __restrict__ g4p,
    const float* __restrict__ g5p, const float* __restrict__ t1w,
    const float* __restrict__ hw, const float* __restrict__ acc,
    float* __restrict__ out, float* __restrict__ scr)
{
    __shared__ float pad[2][2][560];    // h-min rows, main data at [17,529)
    __shared__ float A_lds[3][4][528];  // conv input rows y0-1..y0+2, main [4,516)
    __shared__ float wsh[81];
    __shared__ float sAlpha[3], sBnS[3];
    __shared__ int sI2;

    int t = threadIdx.x;
    int b = blockIdx.x >> 8;            // 4 batches x 256 row-pairs
    int y0b = (blockIdx.x & 255) * 2;
    float g1 = g1p[0], g2 = g2p[0], g3 = g3p[0], g4 = g4p[0], g5 = g5p[0];
    float ig4 = 1.f / g4;

    // ---- prologue: per-block finalize (argsort, alpha, BnS) ----
    if (t == 0) {
        const float invHW = 1.0f / (float)HW_;
        float tot[15];
        #pragma unroll
        for (int s = 0; s < 15; ++s) tot[s] = acc[b * 15 + s];
        float m[3] = {tot[0] * invHW, tot[1] * invHW, tot[2] * invHW};
        int r[3];
        #pragma unroll
        for (int i = 0; i < 3; ++i) {
            int ri = 0;
            #pragma unroll
            for (int j = 0; j < 3; ++j)
                if (j != i && (m[j] < m[i] || (m[j] == m[i] && j < i))) ri++;
            r[i] = ri;   // ascending stable rank
        }
        int idx[3]; float ms[3];
        #pragma unroll
        for (int i = 0; i < 3; ++i) { idx[r[i]] = i; ms[r[i]] = m[i]; }
        sI2 = idx[2];
        float a[3] = {0.f, 0.f, 0.f};
        a[idx[1]] = ms[2] - ms[1];
        a[idx[0]] = ms[2] - ms[0];
        #pragma unroll
        for (int c = 0; c < 3; ++c) {
            sAlpha[c] = a[c];
            sBnS[c] = (tot[3 + c] - a[c] * tot[6 + idx[2] * 3 + c]) * invHW;
        }
        if (blockIdx.x == 0) out[O_g3] = g3;
    }
    if (t < 81) wsh[t] = hw[t];
    __syncthreads();

    int rrow = t >> 7;                  // row within block: 0..1
    int xq = t & 127;                   // float4 col
    int x0 = xq * 4;
    size_t pb = (size_t)b * (CHW_ / 4);
    size_t q = (size_t)(y0b + rrow) * 128 + xq;   // float4 offset in plane
    float wc[3] = {t1w[0], t1w[1], t1w[2]};
    int i2 = sI2;
    const float4* I4p = (const float4*)I;
    const float4* tp4p = (const float4*)t_p;
    const float4* H4p = (const float4*)Hm;
    const float4* X4p = (const float4*)Xm;
    const float4* J4p = (const float4*)J;
    const float4* u4p = (const float4*)u;
    const float4* v4p = (const float4*)v;
    const float4* Y4p = (const float4*)Y;
    const float4* G4p = (const float4*)G;
    float4* o4 = (float4*)out;

    // ---- phase 1: main 2 rows, full elementwise ----
    float4 Jl = J4p[pb + (size_t)i2 * HW4_ + q];
    float4 t1 = make_float4(0.f, 0.f, 0.f, 0.f);
    float4 Isv[3], Xsv[3]; float Bsv[3];
    const float den2 = LAM2 + g4;
    #pragma unroll
    for (int c = 0; c < 3; ++c) {
        size_t o = pb + (size_t)c * HW4_ + q;
        float4 I4 = I4p[o], tp4 = tp4p[o], H4 = H4p[o], X4 = X4p[o], Jv = J4p[o];
        float al = sAlpha[c], Bnv = sBnS[c];
        float wcc = wc[c];
#define STEP1(m) { \
        float d_ = (Jv.m + al * Jl.m) - Bnv; \
        float tnr_ = (LAM2 * tp4.m + g4 * H4.m - (Bnv - I4.m) * d_ - X4.m) / (d_ * d_ + den2); \
        t1.m += wcc * tnr_; }
        STEP1(x) STEP1(y) STEP1(z) STEP1(w)
#undef STEP1
        Isv[c] = I4; Xsv[c] = X4; Bsv[c] = Bnv;
    }
    float g345 = g3 + g4 + g5;
    float4 invDen;
    invDen.x = 1.f / (t1.x * t1.x + g345);
    invDen.y = 1.f / (t1.y * t1.y + g345);
    invDen.z = 1.f / (t1.z * t1.z + g345);
    invDen.w = 1.f / (t1.w * t1.w + g345);
    float invDu = 1.f / (g1 + g4), invDv = 1.f / (g2 + g5);
    float4 cu = make_float4(1e30f, 1e30f, 1e30f, 1e30f);
    float4 cv = cu;
    #pragma unroll
    for (int c = 0; c < 3; ++c) {
        size_t o = pb + (size_t)c * HW4_ + q;
        float4 u4 = u4p[o], v4 = v4p[o], Y4 = Y4p[o], G4 = G4p[o];
        float Bnv = Bsv[c];
        float4 Jn4, un4, vn4, Yn4;
#define STEP2(m) { \
        float Jn_ = (t1.m * (Isv[c].m - Bnv * (1.f - t1.m)) + g3 * G4.m + g4 * u4.m \
                     - g5 * v4.m - Y4.m + g5) * invDen.m; \
        float un_ = (g1 * u4.m + g4 * Jn_) * invDu; \
        float vn_ = (g2 * v4.m - g5 * Jn_ + g5) * invDv; \
        Jn4.m = Jn_; un4.m = un_; vn4.m = vn_; \
        Yn4.m = Y4.m + g3 * (Jn_ - G4.m); \
        cu.m = fminf(cu.m, un_); cv.m = fminf(cv.m, vn_); }
        STEP2(x) STEP2(y) STEP2(z) STEP2(w)
#undef STEP2
        nt_store4(make_float4(Bnv, Bnv, Bnv, Bnv), &o4[O_Bn / 4 + o]);
        nt_store4(t1,  &o4[O_tn / 4 + o]);
        nt_store4(Jn4, &o4[O_Jn / 4 + o]);
        nt_store4(G4,  &o4[O_G  / 4 + o]);
        nt_store4(un4, &o4[O_un / 4 + o]);
        nt_store4(vn4, &o4[O_vn / 4 + o]);
        nt_store4(Yn4, &o4[O_Yn / 4 + o]);
        // conv input A center rows
        float4 A4;
        A4.x = t1.x + Xsv[c].x * ig4; A4.y = t1.y + Xsv[c].y * ig4;
        A4.z = t1.z + Xsv[c].z * ig4; A4.w = t1.w + Xsv[c].w * ig4;
        *(float4*)(&A_lds[c][1 + rrow][4 + x0]) = A4;
    }
    // h-min staging
    pad[0][rrow][17 + x0 + 0] = cu.x;
    pad[0][rrow][17 + x0 + 1] = cu.y;
    pad[0][rrow][17 + x0 + 2] = cu.z;
    pad[0][rrow][17 + x0 + 3] = cu.w;
    pad[1][rrow][17 + x0 + 0] = cv.x;
    pad[1][rrow][17 + x0 + 1] = cv.y;
    pad[1][rrow][17 + x0 + 2] = cv.z;
    pad[1][rrow][17 + x0 + 3] = cv.w;

    // ---- phase 2: halo rows (y0-1, y0+2) — t1 only, build A rows 0/3 ----
    {
        int hr = (rrow == 0) ? (y0b - 1) : (y0b + 2);
        int ar = (rrow == 0) ? 0 : 3;
        if (hr >= 0 && hr < H_) {
            size_t hq = (size_t)hr * 128 + xq;
            float4 Jlh = J4p[pb + (size_t)i2 * HW4_ + hq];
            float4 t1h = make_float4(0.f, 0.f, 0.f, 0.f);
            float4 Xh[3];
            #pragma unroll
            for (int c = 0; c < 3; ++c) {
                size_t o = pb + (size_t)c * HW4_ + hq;
                float4 I4 = I4p[o], tp4 = tp4p[o], H4 = H4p[o], X4 = X4p[o], Jv = J4p[o];
                float al = sAlpha[c], Bnv = sBnS[c];
                float wcc = wc[c];
#define STEP1H(m) { \
                float d_ = (Jv.m + al * Jlh.m) - Bnv; \
                float tnr_ = (LAM2 * tp4.m + g4 * H4.m - (Bnv - I4.m) * d_ - X4.m) / (d_ * d_ + den2); \
                t1h.m += wcc * tnr_; }
                STEP1H(x) STEP1H(y) STEP1H(z) STEP1H(w)
#undef STEP1H
                Xh[c] = X4;
            }
            #pragma unroll
            for (int c = 0; c < 3; ++c) {
                float4 A4;
                A4.x = t1h.x + Xh[c].x * ig4; A4.y = t1h.y + Xh[c].y * ig4;
                A4.z = t1h.z + Xh[c].z * ig4; A4.w = t1h.w + Xh[c].w * ig4;
                *(float4*)(&A_lds[c][ar][4 + x0]) = A4;
            }
        } else {
            float4 z = make_float4(0.f, 0.f, 0.f, 0.f);
            #pragma unroll
            for (int c = 0; c < 3; ++c)
                *(float4*)(&A_lds[c][ar][4 + x0]) = z;
        }
    }
    if (t < 24) {                        // x-halo zeros: cells [3] and [516]
        int pair = t >> 1, side = t & 1;
        A_lds[pair >> 2][pair & 3][side ? 516 : 3] = 0.f;
    }
    __syncthreads();

    // ---- pad reflect edge fill ----
    if (t < 136) {                      // 4 rows x 34 cells
        int which = t / 34, e = t % 34;
        int tens = which >> 1, rw = which & 1;
        int j   = (e < 17) ? e : (529 + (e - 17));
        int src = (e < 17) ? (34 - j) : (1056 - j);
        pad[tens][rw][j] = pad[tens][rw][src];
    }
    __syncthreads();

    // ---- phase 3: horizontal 35-tap reflect min -> scr ----
    int yg = y0b + rrow;
    #pragma unroll
    for (int tens = 0; tens < 2; ++tens) {
        const float* rowp = &pad[tens][rrow][0];
        const float4* rp4 = (const float4*)(rowp + x0);   // 16B-aligned
        float4 qv = rp4[0];
        float a0 = qv.x, a1 = qv.y, a2 = qv.z;
        float mc = qv.w;
        #pragma unroll
        for (int i = 1; i < 8; ++i) {
            qv = rp4[i];
            mc = fminf(mc, fminf(fminf(qv.x, qv.y), fminf(qv.z, qv.w)));
        }
        qv = rp4[8];
        mc = fminf(mc, fminf(qv.x, fminf(qv.y, qv.z)));
        float a35 = qv.w;
        qv = rp4[9];
        float a36 = qv.x, a37 = qv.y;
        float4 r;
        r.x = fminf(fminf(a0, a1), fminf(a2, mc));
        r.y = fminf(fminf(a1, a2), fminf(mc, a35));
        r.z = fminf(fminf(a2, mc), fminf(a35, a36));
        r.w = fminf(fminf(mc, a35), fminf(a36, a37));
        *(float4*)(scr + (size_t)(tens * 4 + b) * HW_ + yg * W_ + x0) = r;
    }

    // ---- phase 4: 3x3 zero-pad conv from A_lds -> Hn, Xn ----
    {
        int tl = t & 127, r_out = t >> 7;
        float cacc[3][4] = {{0.f,0.f,0.f,0.f},{0.f,0.f,0.f,0.f},{0.f,0.f,0.f,0.f}};
        #pragma unroll
        for (int i = 0; i < 3; ++i) {
            #pragma unroll
            for (int ky = 0; ky < 3; ++ky) {
                const float* Ar = &A_lds[i][r_out + ky][0];
                const float* wp0 = &wsh[0 * 27 + i * 9 + ky * 3];
                const float* wp1 = &wsh[1 * 27 + i * 9 + ky * 3];
                const float* wp2 = &wsh[2 * 27 + i * 9 + ky * 3];
                float w00 = wp0[0], w01 = wp0[1], w02 = wp0[2];
                float w10 = wp1[0], w11 = wp1[1], w12 = wp1[2];
                float w20 = wp2[0], w21 = wp2[1], w22 = wp2[2];
                #pragma unroll
                for (int j = 0; j < 4; ++j) {
                    int x = tl + 128 * j;
                    float am = Ar[3 + x], a0 = Ar[4 + x], ap = Ar[5 + x];
                    cacc[0][j] += w00 * am + w01 * a0 + w02 * ap;
                    cacc[1][j] += w10 * am + w11 * a0 + w12 * ap;
                    cacc[2][j] += w20 * am + w21 * a0 + w22 * ap;
                }
            }
        }
        int ygc = y0b + r_out;
        #pragma unroll
        for (int o = 0; o < 3; ++o) {
            #pragma unroll
            for (int j = 0; j < 4; ++j) {
                int x = tl + 128 * j;
                size_t oo = (size_t)(b * 3 + o) * HW_ + (size_t)ygc * W_ + x;
                float hn = cacc[o][j];
                float Ac = A_lds[o][r_out + 1][4 + x];
                __builtin_nontemporal_store(hn, &out[O_Hn + oo]);
                __builtin_nontemporal_store(g4 * (Ac - hn), &out[O_Xn + oo]);
            }
        }
    }
}

// ---- Pass C: vertical 35-tap reflect min + soft threshold -> Pn/Qn ----
__global__ __launch_bounds__(256) void kVMin(const float* __restrict__ scr,
                                             const float* __restrict__ g1p,
                                             float* __restrict__ out) {
    int t = threadIdx.x;
    int tensor = blockIdx.x >> 10;
    int lid = ((blockIdx.x & 1023) << 8) + t;
    int b = lid >> 16, qq = lid & (HW4_ - 1);
    int y = qq >> 7, xq = (qq & 127) << 2;
    const float* R = scr + (size_t)(tensor * 4 + b) * HW_;
    float4 m = make_float4(1e30f, 1e30f, 1e30f, 1e30f);
    #pragma unroll
    for (int k = 0; k < 35; ++k) {
        int yy = y + k - 17;
        yy = yy < 0 ? -yy : (yy >= H_ ? 2 * H_ - 2 - yy : yy);
        float4 r4 = *(const float4*)(R + yy * W_ + xq);
        m.x = fminf(m.x, r4.x); m.y = fminf(m.y, r4.y);
        m.z = fminf(m.z, r4.z); m.w = fminf(m.w, r4.w);
    }
    float lam = 1.0f / g1p[0];            // lam4/g1 == lam5/g1 == 1/g1
    float4 r;
#define SOFT(m_, r_) { float s = (m_ > 0.f) ? 1.f : (m_ < 0.f ? -1.f : 0.f); \
                       r_ = s * fmaxf(fabsf(m_) - lam, 0.f); }
    SOFT(m.x, r.x) SOFT(m.y, r.y) SOFT(m.z, r.z) SOFT(m.w, r.w)
#undef SOFT
    nt_store4(r, (float4*)(out + (tensor ? O_Qn : O_Pn) + b * HW_ + y * W_ + xq));
}

extern "C" void kernel_launch(void* const* d_in, const int* in_sizes, int n_in,
                              void* d_out, int out_size, void* d_ws, size_t ws_size,
                              hipStream_t stream) {
    (void)in_sizes; (void)n_in; (void)out_size; (void)ws_size;
    const float* I   = (const float*)d_in[0];
    const float* t_p = (const float*)d_in[1];
    const float* B_p = (const float*)d_in[2];
    const float* tt  = (const float*)d_in[4];
    const float* J   = (const float*)d_in[5];
    const float* G   = (const float*)d_in[6];
    const float* Hm  = (const float*)d_in[7];
    const float* u   = (const float*)d_in[10];
    const float* v   = (const float*)d_in[11];
    const float* X   = (const float*)d_in[12];
    const float* Y   = (const float*)d_in[13];
    const float* g1  = (const float*)d_in[14];
    const float* g2  = (const float*)d_in[15];
    const float* g3  = (const float*)d_in[16];
    const float* g4  = (const float*)d_in[17];
    const float* g5  = (const float*)d_in[18];
    const float* t1w = (const float*)d_in[19];
    const float* hw  = (const float*)d_in[20];
    float* out = (float*)d_out;
    float* ws  = (float*)d_ws;

    float* acc = ws + WS_ACC;
    float* scr = ws + WS_SCR;

    hipMemsetAsync(acc, 0, 64 * sizeof(float), stream);
    kRed<<<512, 256, 0, stream>>>(J, tt, B_p, I, acc);
    kMain<<<1024, 256, 0, stream>>>(I, t_p, Hm, X, J, u, v, Y, G,
                                    g1, g2, g3, g4, g5, t1w, hw, acc, out, scr);
    kVMin<<<2048, 256, 0, stream>>>(scr, g1, out);
}